// Round 3
// baseline (1670.232 us; speedup 1.0000x reference)
//
#include <hip/hip_runtime.h>
#include <hip/hip_bf16.h>

typedef unsigned short u16;
typedef unsigned int   u32;

// bf16 (stored as u16) <-> f32. Decode exact; encode round-to-nearest-even.
__device__ __forceinline__ float b2f(u16 v){ return __uint_as_float(((u32)v) << 16); }
__device__ __forceinline__ u16   f2b(float f){
  u32 u = __float_as_uint(f);
  u += 0x7fffu + ((u >> 16) & 1u);
  return (u16)(u >> 16);
}
__device__ __forceinline__ float gelu_exact(float x){
  return 0.5f * x * (1.0f + erff(x * 0.70710678118654752440f));
}

// ---------------------------------------------------------------------------
// K1 (fc1a): out1[row][f], f = k*27+j = sum_{p<53} xe[row][k*53+p] * w1[k][j][p]
// act output COLUMN-MAJOR per chunk: act[f*Bc + rowInChunk], bf16.
// Grid: (Bc/512, 15 k-blocks), block 256, 2 rows/thread.
// ---------------------------------------------------------------------------
__global__ __launch_bounds__(256, 2) void k_fc1a(
    const float* __restrict__ x, const float* __restrict__ w1,
    u16* __restrict__ act, int base, int Bc)
{
  __shared__ __align__(16) float w1s[27*56];
  __shared__ u16 xs[512*57];
  const int tid = threadIdx.x;
  const int k   = blockIdx.y;
  const int rowloc = blockIdx.x * 512;

  for (int e = tid; e < 27*56; e += 256){
    int j = e / 56, p = e - j*56;
    w1s[e] = (p < 53) ? w1[(k*27 + j)*53 + p] : 0.0f;
  }
  #pragma unroll 4
  for (int i = 0; i < 114; ++i){
    int e = i*256 + tid;           // e < 29184 = 512*57
    int r = e / 57, c = e - r*57;
    int col = k*53 + c;
    float v = 0.0f;
    if (c < 53 && col < 784) v = x[(size_t)(base + rowloc + r)*784 + col];
    xs[e] = f2b(v);
  }
  __syncthreads();

  float xb0[56], xb1[56];
  #pragma unroll
  for (int p = 0; p < 56; ++p){
    xb0[p] = b2f(xs[tid*57 + p]);
    xb1[p] = b2f(xs[(tid+256)*57 + p]);
  }
  const int r0 = rowloc + tid;
  #pragma unroll 1
  for (int j = 0; j < 27; ++j){
    float s0a=0.f, s0b=0.f, s1a=0.f, s1b=0.f;
    #pragma unroll
    for (int i = 0; i < 14; ++i){
      const float4 w = *(const float4*)&w1s[j*56 + 4*i];   // wave-uniform broadcast
      s0a = fmaf(w.x, xb0[4*i+0], s0a); s0b = fmaf(w.y, xb0[4*i+1], s0b);
      s0a = fmaf(w.z, xb0[4*i+2], s0a); s0b = fmaf(w.w, xb0[4*i+3], s0b);
      s1a = fmaf(w.x, xb1[4*i+0], s1a); s1b = fmaf(w.y, xb1[4*i+1], s1b);
      s1a = fmaf(w.z, xb1[4*i+2], s1a); s1b = fmaf(w.w, xb1[4*i+3], s1b);
    }
    const size_t bf = (size_t)(k*27 + j) * (size_t)Bc;
    act[bf + r0]       = f2b(s0a + s0b);
    act[bf + r0 + 256] = f2b(s1a + s1b);
  }
}

// ---------------------------------------------------------------------------
// K2 (fc1b): h1[m], m = s*15+l = gelu( sum_{r<27} out1[r*15+l]*w2[l][s][r] + b[m] )
// for m<392, else 0. In-place on act (disjoint per-thread (row, l-class) sets).
// Block 256 = 2 wave-pairs: waves 0-1 -> l 0..7, waves 2-3 -> l 8..14, so each
// wave's 64 lanes cover 64 CONSECUTIVE rows with one l-set -> coalesced streams.
// Grid Bc/128.
// ---------------------------------------------------------------------------
__global__ __launch_bounds__(256, 2) void k_fc1b(
    const float* __restrict__ w2, const float* __restrict__ b1,
    u16* act, int Bc)
{
  __shared__ __align__(16) float w2s[15*27*28];
  __shared__ float b1s[392];
  const int tid = threadIdx.x;
  for (int e = tid; e < 15*27*28; e += 256){
    int a = e / 28, r = e - a*28;
    w2s[e] = (r < 27) ? w2[a*27 + r] : 0.0f;
  }
  for (int e = tid; e < 392; e += 256) b1s[e] = b1[e];
  __syncthreads();

  const int row = blockIdx.x*128 + (tid & 127);
  const int q   = tid >> 7;                     // wave-uniform l-half
  const int l0 = q * 8, l1 = q ? 15 : 8;
  for (int l = l0; l < l1; ++l){
    float t[28];
    #pragma unroll
    for (int r = 0; r < 27; ++r) t[r] = b2f(act[(size_t)(r*15 + l)*Bc + row]);
    t[27] = 0.0f;
    #pragma unroll 1
    for (int s = 0; s < 27; ++s){
      const float* wp = &w2s[(l*27 + s)*28];
      float va = 0.f, vb = 0.f;
      #pragma unroll
      for (int i = 0; i < 7; ++i){
        const float4 w = *(const float4*)&wp[4*i];
        va = fmaf(w.x, t[4*i+0], va); vb = fmaf(w.y, t[4*i+1], vb);
        va = fmaf(w.z, t[4*i+2], va); vb = fmaf(w.w, t[4*i+3], vb);
      }
      const int m = s*15 + l;
      float h = 0.0f;
      if (m < 392) h = gelu_exact(va + vb + b1s[m]);
      act[(size_t)m*Bc + row] = f2b(h);
    }
  }
}

// ---------------------------------------------------------------------------
// K3 (fc2): o2[k*9+j] = sum_{p<27} h1[k*27+p]*w1_2[k][j][p]  (k-loop FULLY
// unrolled -> o2 stays in VGPRs, no scratch);  then
// h2[s*15+l] = gelu(sum_r o2[r*15+l]*w2_2[l][s][r] + b2)  for m<128, else 0,
// streamed straight to ws (column-major bf16, 135 features).
// Peak live ~180 VGPRs. Block 256, grid Bc/256.
// ---------------------------------------------------------------------------
__global__ __launch_bounds__(256, 2) void k_fc2(
    const u16* __restrict__ h1t, const float* __restrict__ w1_2,
    const float* __restrict__ w2_2, const float* __restrict__ b2,
    u16* __restrict__ h2t, int Bc)
{
  __shared__ __align__(16) float w12s[135*28];
  __shared__ __align__(16) float w22s[135*12];
  __shared__ float b2s[128];
  const int tid = threadIdx.x;
  for (int e = tid; e < 135*28; e += 256){ int a=e/28, p=e-a*28; w12s[e] = (p<27)? w1_2[a*27+p] : 0.f; }
  for (int e = tid; e < 135*12; e += 256){ int a=e/12, r=e-a*12; w22s[e] = (r< 9)? w2_2[a*9 +r] : 0.f; }
  for (int e = tid; e < 128;    e += 256) b2s[e] = b2[e];
  __syncthreads();

  const int rloc = blockIdx.x*256 + tid;
  float o2[135];
  #pragma unroll
  for (int k = 0; k < 15; ++k){            // FULLY unrolled: static o2 indices
    float hb[28];
    #pragma unroll
    for (int p = 0; p < 27; ++p) hb[p] = b2f(h1t[(size_t)(k*27 + p)*Bc + rloc]);
    hb[27] = 0.0f;
    #pragma unroll
    for (int j = 0; j < 9; ++j){
      const float* wp = &w12s[(k*9 + j)*28];
      float va = 0.f, vb = 0.f;
      #pragma unroll
      for (int i = 0; i < 7; ++i){
        const float4 w = *(const float4*)&wp[4*i];
        va = fmaf(w.x, hb[4*i+0], va); vb = fmaf(w.y, hb[4*i+1], vb);
        va = fmaf(w.z, hb[4*i+2], va); vb = fmaf(w.w, hb[4*i+3], vb);
      }
      o2[k*9 + j] = va + vb;
    }
  }
  #pragma unroll
  for (int l = 0; l < 15; ++l){
    #pragma unroll
    for (int s = 0; s < 9; ++s){
      const float* wp = &w22s[(l*9 + s)*12];
      float v = 0.f;
      #pragma unroll
      for (int r = 0; r < 9; ++r) v = fmaf(wp[r], o2[r*15 + l], v);
      const int m = s*15 + l;
      float h = (m < 128) ? gelu_exact(v + b2s[m]) : 0.0f;
      h2t[(size_t)m*Bc + rloc] = f2b(h);   // coalesced u16 stream
    }
  }
}

// ---------------------------------------------------------------------------
// K4 (fc3 + fc4 + log_softmax): h2 consumed 9-at-a-time (never 135 live).
// o3[75] + h3[50] peak live ~150 VGPRs. Output staged via LDS for coalesced
// f32 stores. Block 256, grid Bc/256.
// ---------------------------------------------------------------------------
__global__ __launch_bounds__(256, 2) void k_fc34(
    const u16* __restrict__ h2t,
    const float* __restrict__ w1_3, const float* __restrict__ w2_3, const float* __restrict__ b3,
    const float* __restrict__ w1_4, const float* __restrict__ w2_4, const float* __restrict__ b4,
    float* __restrict__ out, int base, int Bc)
{
  __shared__ __align__(16) float w13s[75*12];
  __shared__ __align__(16) float w23s[75*8];
  __shared__ float b3s[64];
  __shared__ __align__(16) float w14s[10*8];
  __shared__ float w24s[10];
  __shared__ float b4s[10];
  __shared__ float outS[256*10];
  const int tid = threadIdx.x;
  for (int e = tid; e < 75*12;  e += 256){ int a=e/12, p=e-a*12; w13s[e] = (p< 9)? w1_3[a*9 +p] : 0.f; }
  for (int e = tid; e < 75*8;   e += 256){ int a=e/8,  r=e-a*8;  w23s[e] = (r< 5)? w2_3[a*5 +r] : 0.f; }
  for (int e = tid; e < 64;     e += 256) b3s[e] = b3[e];
  for (int e = tid; e < 80;     e += 256){ int c=e/8,  p=e-c*8;  w14s[e] = (p< 5)? w1_4[c*5 +p] : 0.f; }
  if (tid < 10){ w24s[tid] = w2_4[tid]; b4s[tid] = b4[tid]; }
  __syncthreads();

  const int rloc = blockIdx.x*256 + tid;

  // ---- fc3a: o3[k*5+j] = sum_{p<9} h2[k*9+p] * w1_3[k][j][p]
  float o3[75];
  #pragma unroll
  for (int k = 0; k < 15; ++k){
    float hb[12];
    #pragma unroll
    for (int p = 0; p < 9; ++p) hb[p] = b2f(h2t[(size_t)(k*9 + p)*Bc + rloc]);
    hb[9] = 0.f; hb[10] = 0.f; hb[11] = 0.f;
    #pragma unroll
    for (int j = 0; j < 5; ++j){
      const float* wp = &w13s[(k*5 + j)*12];
      float v = 0.f;
      #pragma unroll
      for (int i = 0; i < 3; ++i){
        const float4 w = *(const float4*)&wp[4*i];
        v = fmaf(w.x, hb[4*i+0], v); v = fmaf(w.y, hb[4*i+1], v);
        v = fmaf(w.z, hb[4*i+2], v); v = fmaf(w.w, hb[4*i+3], v);
      }
      o3[k*5 + j] = v;
    }
  }
  // ---- fc3b + gelu (only m<50 feeds fc4)
  float h3[50];
  #pragma unroll
  for (int l = 0; l < 15; ++l){
    #pragma unroll
    for (int s = 0; s < 5; ++s){
      const int m = s*15 + l;
      if (m < 50){
        const float* wp = &w23s[(l*5 + s)*8];
        float v = 0.f;
        v = fmaf(wp[0], o3[     l], v);
        v = fmaf(wp[1], o3[15 + l], v);
        v = fmaf(wp[2], o3[30 + l], v);
        v = fmaf(wp[3], o3[45 + l], v);
        v = fmaf(wp[4], o3[60 + l], v);
        h3[m] = gelu_exact(v + b3s[m]);
      }
    }
  }
  // ---- fc4
  float v[10];
  #pragma unroll
  for (int c = 0; c < 10; ++c){
    const float* wp = &w14s[c*8];
    float sacc = 0.f;
    #pragma unroll
    for (int p = 0; p < 5; ++p) sacc = fmaf(wp[p], h3[c*5 + p], sacc);
    v[c] = fmaf(sacc, w24s[c], b4s[c]);
  }
  // ---- log_softmax
  float mx = v[0];
  #pragma unroll
  for (int c = 1; c < 10; ++c) mx = fmaxf(mx, v[c]);
  float sum = 0.f;
  #pragma unroll
  for (int c = 0; c < 10; ++c) sum += expf(v[c] - mx);
  const float lse = mx + logf(sum);
  #pragma unroll
  for (int c = 0; c < 10; ++c) outS[tid*10 + c] = v[c] - lse;   // stride 10: 2-way bank alias = free
  __syncthreads();
  const size_t blockOut = (size_t)(base + blockIdx.x*256) * 10;
  #pragma unroll
  for (int i = 0; i < 10; ++i){
    int e = i*256 + tid;
    out[blockOut + e] = outS[e];   // coalesced f32 stores
  }
}

// ---------------------------------------------------------------------------
extern "C" void kernel_launch(void* const* d_in, const int* in_sizes, int n_in,
                              void* d_out, int out_size, void* d_ws, size_t ws_size,
                              hipStream_t stream)
{
  const float* x     = (const float*)d_in[0];
  const float* f1w1  = (const float*)d_in[1];
  const float* f1w2  = (const float*)d_in[2];
  const float* f1b   = (const float*)d_in[3];
  const float* f2w1  = (const float*)d_in[4];
  const float* f2w2  = (const float*)d_in[5];
  const float* f2b   = (const float*)d_in[6];
  const float* f3w1  = (const float*)d_in[7];
  const float* f3w2  = (const float*)d_in[8];
  const float* f3b   = (const float*)d_in[9];
  const float* f4w1  = (const float*)d_in[10];
  const float* f4w2  = (const float*)d_in[11];
  const float* f4b   = (const float*)d_in[12];
  const int B = in_sizes[0] / 784;           // 65536
  (void)n_in; (void)out_size;

  // ws layout per chunk of Bc rows: act (405 x Bc bf16) then h2t (135 x Bc bf16).
  const size_t perRow = 540 * sizeof(u16);   // 1080 B
  int Rc = B;
  if (ws_size < (size_t)B * perRow){
    size_t rows = ws_size / perRow;
    Rc = (int)(rows & ~(size_t)511);
    if (Rc < 512) Rc = 512;
  }
  for (int base = 0; base < B; base += Rc){
    const int Bc = (B - base < Rc) ? (B - base) : Rc;
    u16* act = (u16*)d_ws;
    u16* h2t = act + (size_t)405 * Bc;
    k_fc1a<<<dim3(Bc/512, 15), 256, 0, stream>>>(x, f1w1, act, base, Bc);
    k_fc1b<<<dim3(Bc/128), 256, 0, stream>>>(f1w2, f1b, act, Bc);
    k_fc2 <<<dim3(Bc/256), 256, 0, stream>>>(act, f2w1, f2w2, f2b, h2t, Bc);
    k_fc34<<<dim3(Bc/256), 256, 0, stream>>>(h2t, f3w1, f3w2, f3b,
                                             f4w1, f4w2, f4b, (float*)d_out, base, Bc);
  }
}

// Round 4
// 632.916 us; speedup vs baseline: 2.6389x; 2.6389x over previous
//
#include <hip/hip_runtime.h>
#include <hip/hip_bf16.h>

typedef unsigned short u16;
typedef unsigned int   u32;

// bf16 (stored as u16) <-> f32. Decode exact; encode round-to-nearest-even.
__device__ __forceinline__ float b2f(u16 v){ return __uint_as_float(((u32)v) << 16); }
__device__ __forceinline__ u16   f2b(float f){
  u32 u = __float_as_uint(f);
  u += 0x7fffu + ((u >> 16) & 1u);
  return (u16)(u >> 16);
}
__device__ __forceinline__ float gelu_exact(float x){
  return 0.5f * x * (1.0f + erff(x * 0.70710678118654752440f));
}

// ---------------------------------------------------------------------------
// K1 (fc1a): UNCHANGED from round 3 (control kernel — want its counters).
// out1[row][f], f=k*27+j = sum_{p<53} xe[row][k*53+p]*w1[k][j][p]
// act column-major bf16: act[f*Bc + row]. Grid (Bc/512, 15), block 256.
// ---------------------------------------------------------------------------
__global__ __launch_bounds__(256, 2) void k_fc1a(
    const float* __restrict__ x, const float* __restrict__ w1,
    u16* __restrict__ act, int base, int Bc)
{
  __shared__ __align__(16) float w1s[27*56];
  __shared__ u16 xs[512*57];
  const int tid = threadIdx.x;
  const int k   = blockIdx.y;
  const int rowloc = blockIdx.x * 512;

  for (int e = tid; e < 27*56; e += 256){
    int j = e / 56, p = e - j*56;
    w1s[e] = (p < 53) ? w1[(k*27 + j)*53 + p] : 0.0f;
  }
  #pragma unroll 4
  for (int i = 0; i < 114; ++i){
    int e = i*256 + tid;
    int r = e / 57, c = e - r*57;
    int col = k*53 + c;
    float v = 0.0f;
    if (c < 53 && col < 784) v = x[(size_t)(base + rowloc + r)*784 + col];
    xs[e] = f2b(v);
  }
  __syncthreads();

  float xb0[56], xb1[56];
  #pragma unroll
  for (int p = 0; p < 56; ++p){
    xb0[p] = b2f(xs[tid*57 + p]);
    xb1[p] = b2f(xs[(tid+256)*57 + p]);
  }
  const int r0 = rowloc + tid;
  #pragma unroll 1
  for (int j = 0; j < 27; ++j){
    float s0a=0.f, s0b=0.f, s1a=0.f, s1b=0.f;
    #pragma unroll
    for (int i = 0; i < 14; ++i){
      const float4 w = *(const float4*)&w1s[j*56 + 4*i];
      s0a = fmaf(w.x, xb0[4*i+0], s0a); s0b = fmaf(w.y, xb0[4*i+1], s0b);
      s0a = fmaf(w.z, xb0[4*i+2], s0a); s0b = fmaf(w.w, xb0[4*i+3], s0b);
      s1a = fmaf(w.x, xb1[4*i+0], s1a); s1b = fmaf(w.y, xb1[4*i+1], s1b);
      s1a = fmaf(w.z, xb1[4*i+2], s1a); s1b = fmaf(w.w, xb1[4*i+3], s1b);
    }
    const size_t bf = (size_t)(k*27 + j) * (size_t)Bc;
    act[bf + r0]       = f2b(s0a + s0b);
    act[bf + r0 + 256] = f2b(s1a + s1b);
  }
}

// ---------------------------------------------------------------------------
// K2 (fc1b): split over l. Grid (Bc/256, 15), block 256, one row x one l per
// thread. h1[m], m=s*15+l = gelu(sum_r out1[r*15+l]*w2[l][s][r] + b1[m]) for
// m<392 else 0.  In-place on act: block (rowtile,l) reads cols {r*15+l} and
// writes cols {s*15+l} for ITS OWN rows only -> no cross-block hazard.
// ~40 VGPRs, 3.2 KB LDS -> high occupancy (60 waves/CU available).
// ---------------------------------------------------------------------------
__global__ __launch_bounds__(256) void k_fc1b(
    const float* __restrict__ w2, const float* __restrict__ b1,
    u16* act, int Bc)
{
  __shared__ __align__(16) float w2s[27*28];
  __shared__ float b1s[27];
  const int tid = threadIdx.x;
  const int l   = blockIdx.y;
  for (int e = tid; e < 27*28; e += 256){
    int s = e / 28, r = e - s*28;
    w2s[e] = (r < 27) ? w2[(l*27 + s)*27 + r] : 0.0f;
  }
  if (tid < 27){
    int m = tid*15 + l;
    b1s[tid] = (m < 392) ? b1[m] : 0.0f;
  }
  __syncthreads();

  const int row = blockIdx.x*256 + tid;
  float t[28];
  #pragma unroll
  for (int r = 0; r < 27; ++r) t[r] = b2f(act[(size_t)(r*15 + l)*Bc + row]);
  t[27] = 0.0f;
  #pragma unroll
  for (int s = 0; s < 27; ++s){
    const float* wp = &w2s[s*28];
    float va = 0.f, vb = 0.f;
    #pragma unroll
    for (int i = 0; i < 7; ++i){
      const float4 w = *(const float4*)&wp[4*i];
      va = fmaf(w.x, t[4*i+0], va); vb = fmaf(w.y, t[4*i+1], vb);
      va = fmaf(w.z, t[4*i+2], va); vb = fmaf(w.w, t[4*i+3], vb);
    }
    const int m = s*15 + l;
    float h = (m < 392) ? gelu_exact(va + vb + b1s[s]) : 0.0f;
    act[(size_t)m*Bc + row] = f2b(h);
  }
}

// ---------------------------------------------------------------------------
// K3 (fc2a): split over k. Grid (Bc/256, 15). o2[k*9+j] =
// sum_{p<27} h1[k*27+p]*w1_2[k][j][p]; write o2t column-major bf16.
// ---------------------------------------------------------------------------
__global__ __launch_bounds__(256) void k_fc2a(
    const u16* __restrict__ h1t, const float* __restrict__ w1_2,
    u16* __restrict__ o2t, int Bc)
{
  __shared__ __align__(16) float ws[9*28];
  const int tid = threadIdx.x;
  const int k   = blockIdx.y;
  for (int e = tid; e < 9*28; e += 256){
    int j = e / 28, p = e - j*28;
    ws[e] = (p < 27) ? w1_2[(k*9 + j)*27 + p] : 0.0f;
  }
  __syncthreads();

  const int row = blockIdx.x*256 + tid;
  float hb[28];
  #pragma unroll
  for (int p = 0; p < 27; ++p) hb[p] = b2f(h1t[(size_t)(k*27 + p)*Bc + row]);
  hb[27] = 0.0f;
  #pragma unroll
  for (int j = 0; j < 9; ++j){
    const float* wp = &ws[j*28];
    float va = 0.f, vb = 0.f;
    #pragma unroll
    for (int i = 0; i < 7; ++i){
      const float4 w = *(const float4*)&wp[4*i];
      va = fmaf(w.x, hb[4*i+0], va); vb = fmaf(w.y, hb[4*i+1], vb);
      va = fmaf(w.z, hb[4*i+2], va); vb = fmaf(w.w, hb[4*i+3], vb);
    }
    o2t[(size_t)(k*9 + j)*Bc + row] = f2b(va + vb);
  }
}

// ---------------------------------------------------------------------------
// K4 (fc2b): split over l. Grid (Bc/256, 15). h2[m], m=s*15+l =
// gelu(sum_{r<9} o2[r*15+l]*w2_2[l][s][r] + b2[m]) for m<128 else 0.
// ---------------------------------------------------------------------------
__global__ __launch_bounds__(256) void k_fc2b(
    const u16* __restrict__ o2t, const float* __restrict__ w2_2,
    const float* __restrict__ b2, u16* __restrict__ h2t, int Bc)
{
  __shared__ float ws[9*9];
  __shared__ float b2s[9];
  const int tid = threadIdx.x;
  const int l   = blockIdx.y;
  if (tid < 81) ws[tid] = w2_2[l*81 + tid];
  if (tid < 9){
    int m = tid*15 + l;
    b2s[tid] = (m < 128) ? b2[m] : 0.0f;
  }
  __syncthreads();

  const int row = blockIdx.x*256 + tid;
  float t[9];
  #pragma unroll
  for (int r = 0; r < 9; ++r) t[r] = b2f(o2t[(size_t)(r*15 + l)*Bc + row]);
  #pragma unroll
  for (int s = 0; s < 9; ++s){
    const float* wp = &ws[s*9];
    float v = 0.f;
    #pragma unroll
    for (int r = 0; r < 9; ++r) v = fmaf(wp[r], t[r], v);
    const int m = s*15 + l;
    float h = (m < 128) ? gelu_exact(v + b2s[s]) : 0.0f;
    h2t[(size_t)m*Bc + row] = f2b(h);
  }
}

// ---------------------------------------------------------------------------
// K5 (fc3a): split over k. Grid (Bc/256, 15). o3[k*5+j] =
// sum_{p<9} h2[k*9+p]*w1_3[k][j][p]; o3t column-major bf16.
// ---------------------------------------------------------------------------
__global__ __launch_bounds__(256) void k_fc3a(
    const u16* __restrict__ h2t, const float* __restrict__ w1_3,
    u16* __restrict__ o3t, int Bc)
{
  __shared__ float ws[5*9];
  const int tid = threadIdx.x;
  const int k   = blockIdx.y;
  if (tid < 45) ws[tid] = w1_3[k*45 + tid];
  __syncthreads();

  const int row = blockIdx.x*256 + tid;
  float hb[9];
  #pragma unroll
  for (int p = 0; p < 9; ++p) hb[p] = b2f(h2t[(size_t)(k*9 + p)*Bc + row]);
  #pragma unroll
  for (int j = 0; j < 5; ++j){
    const float* wp = &ws[j*9];
    float v = 0.f;
    #pragma unroll
    for (int p = 0; p < 9; ++p) v = fmaf(wp[p], hb[p], v);
    o3t[(size_t)(k*5 + j)*Bc + row] = f2b(v);
  }
}

// ---------------------------------------------------------------------------
// K6 (fc3b + fc4 + log_softmax): one row/thread, grid Bc/256.
// h3[m]=gelu(sum_r o3[r*15+l]*w2_3[l][s][r]+b3[m]) (m=s*15+l<50) folded
// immediately into fc4 accumulators sacc[c] (c=m/5, static) -> never >40 live.
// Output staged through LDS for coalesced f32 stores.
// ---------------------------------------------------------------------------
__global__ __launch_bounds__(256) void k_fc3b4(
    const u16* __restrict__ o3t,
    const float* __restrict__ w2_3, const float* __restrict__ b3,
    const float* __restrict__ w1_4, const float* __restrict__ w2_4, const float* __restrict__ b4,
    float* __restrict__ out, int base, int Bc)
{
  __shared__ __align__(16) float w23s[75*8];
  __shared__ float b3s[64];
  __shared__ float w14s[10*8];
  __shared__ float w24s[10];
  __shared__ float b4s[10];
  __shared__ float outS[256*10];
  const int tid = threadIdx.x;
  for (int e = tid; e < 75*8; e += 256){ int a=e/8, r=e-a*8; w23s[e] = (r<5)? w2_3[a*5+r] : 0.f; }
  for (int e = tid; e < 64;   e += 256) b3s[e] = b3[e];
  for (int e = tid; e < 80;   e += 256){ int c=e/8, p=e-c*8; w14s[e] = (p<5)? w1_4[c*5+p] : 0.f; }
  if (tid < 10){ w24s[tid] = w2_4[tid]; b4s[tid] = b4[tid]; }
  __syncthreads();

  const int rloc = blockIdx.x*256 + tid;

  float sacc[10];
  #pragma unroll
  for (int c = 0; c < 10; ++c) sacc[c] = 0.0f;

  #pragma unroll
  for (int l = 0; l < 15; ++l){
    float t[5];
    #pragma unroll
    for (int r = 0; r < 5; ++r) t[r] = b2f(o3t[(size_t)(r*15 + l)*Bc + rloc]);
    #pragma unroll
    for (int s = 0; s < 5; ++s){
      const int m = s*15 + l;
      if (m < 50){
        const float* wp = &w23s[(l*5 + s)*8];
        float v = 0.f;
        v = fmaf(wp[0], t[0], v); v = fmaf(wp[1], t[1], v);
        v = fmaf(wp[2], t[2], v); v = fmaf(wp[3], t[3], v);
        v = fmaf(wp[4], t[4], v);
        const float h = gelu_exact(v + b3s[m]);
        const int c = m / 5, p = m - (m/5)*5;      // compile-time constants
        sacc[c] = fmaf(h, w14s[c*8 + p], sacc[c]);
      }
    }
  }
  float v[10];
  #pragma unroll
  for (int c = 0; c < 10; ++c) v[c] = fmaf(sacc[c], w24s[c], b4s[c]);

  float mx = v[0];
  #pragma unroll
  for (int c = 1; c < 10; ++c) mx = fmaxf(mx, v[c]);
  float sum = 0.f;
  #pragma unroll
  for (int c = 0; c < 10; ++c) sum += expf(v[c] - mx);
  const float lse = mx + logf(sum);
  #pragma unroll
  for (int c = 0; c < 10; ++c) outS[tid*10 + c] = v[c] - lse;
  __syncthreads();
  const size_t blockOut = (size_t)(base + blockIdx.x*256) * 10;
  #pragma unroll
  for (int i = 0; i < 10; ++i){
    int e = i*256 + tid;
    out[blockOut + e] = outS[e];
  }
}

// ---------------------------------------------------------------------------
extern "C" void kernel_launch(void* const* d_in, const int* in_sizes, int n_in,
                              void* d_out, int out_size, void* d_ws, size_t ws_size,
                              hipStream_t stream)
{
  const float* x     = (const float*)d_in[0];
  const float* f1w1  = (const float*)d_in[1];
  const float* f1w2  = (const float*)d_in[2];
  const float* f1b   = (const float*)d_in[3];
  const float* f2w1  = (const float*)d_in[4];
  const float* f2w2  = (const float*)d_in[5];
  const float* f2b   = (const float*)d_in[6];
  const float* f3w1  = (const float*)d_in[7];
  const float* f3w2  = (const float*)d_in[8];
  const float* f3b   = (const float*)d_in[9];
  const float* f4w1  = (const float*)d_in[10];
  const float* f4w2  = (const float*)d_in[11];
  const float* f4b   = (const float*)d_in[12];
  const int B = in_sizes[0] / 784;           // 65536
  (void)n_in; (void)out_size;

  // ws per chunk of Bc rows (column-major bf16 streams):
  //   act 405 | o2t 135 | h2t 135 | o3t 75  = 750 u16 per row (1500 B)
  const size_t perRow = 750 * sizeof(u16);
  int Rc = B;
  if (ws_size < (size_t)B * perRow){
    size_t rows = ws_size / perRow;
    Rc = (int)(rows & ~(size_t)511);
    if (Rc < 512) Rc = 512;
  }
  for (int base = 0; base < B; base += Rc){
    const int Bc = (B - base < Rc) ? (B - base) : Rc;
    u16* act = (u16*)d_ws;
    u16* o2t = act + (size_t)405 * Bc;
    u16* h2t = o2t + (size_t)135 * Bc;
    u16* o3t = h2t + (size_t)135 * Bc;
    k_fc1a<<<dim3(Bc/512, 15), 256, 0, stream>>>(x, f1w1, act, base, Bc);
    k_fc1b<<<dim3(Bc/256, 15), 256, 0, stream>>>(f1w2, f1b, act, Bc);
    k_fc2a<<<dim3(Bc/256, 15), 256, 0, stream>>>(act, f2w1, o2t, Bc);
    k_fc2b<<<dim3(Bc/256, 15), 256, 0, stream>>>(o2t, f2w2, f2b, h2t, Bc);
    k_fc3a<<<dim3(Bc/256, 15), 256, 0, stream>>>(h2t, f3w1, o3t, Bc);
    k_fc3b4<<<dim3(Bc/256), 256, 0, stream>>>(o3t, f3w2, f3b,
                                              f4w1, f4w2, f4b, (float*)d_out, base, Bc);
  }
}